// Round 18
// baseline (172.366 us; speedup 1.0000x reference)
//
#include <hip/hip_runtime.h>

// ---------------------------------------------------------------------------
// VectorQuantizer R18: one 512-thread block per CU (grid 256 = 1/CU exact).
// R17 win (32->16 phases: 83->74us fused) isolated per-phase overhead as the
// live lever. R18 halves it again (8 phases x 128 codes, 64KB chunks, 2-buf)
// AND halves per-CU staging traffic (one block's staged B-tile serves 8
// waves instead of 4; 1MB -> 512KB L2->LDS per CU). Per-wave work identical
// to R16/R17 (16 rows x 1024 codes, two-chain 16x16x32 MFMA, top-3 +
// escalation tracking, bounded resolve). Packing: capacity 1, grid 1/CU --
// perfectly even (the ledger's requirement).
// Pre-commit: if total >= 85us, revert to R17 and declare plateau.
// Exactness: unchanged (margin superset + exact fp32 rescore + tie-break).
// ---------------------------------------------------------------------------

constexpr int Mrows = 32768;
constexpr int Ddim  = 256;
constexpr int Kcode = 1024;

constexpr int   CAP    = 6;      // overflow (n>6) -> bounded full scan
constexpr float MARGIN = 0.25f;

typedef unsigned long long u64;
typedef unsigned short ushort_t;
typedef __attribute__((ext_vector_type(8))) short bf16x8;
typedef __attribute__((ext_vector_type(4))) float f32x4;

__device__ inline u64 packKey(float v, int idx) {
    unsigned u = __float_as_uint(v);
    u = (u & 0x80000000u) ? ~u : (u | 0x80000000u);   // order-preserving
    return ((u64)u << 32) | (unsigned)idx;
}
__device__ inline float unpackScore(u64 k) {
    unsigned v = (unsigned)(k >> 32);
    unsigned orig = (v & 0x80000000u) ? (v ^ 0x80000000u) : ~v;
    return __uint_as_float(orig);
}
__device__ inline ushort_t f2bf(float f) {   // RTN-even
    unsigned u = __float_as_uint(f);
    return (ushort_t)((u + 0x7fffu + ((u >> 16) & 1u)) >> 16);
}
__device__ inline void gload_lds16(const void* g, void* l) {
    __builtin_amdgcn_global_load_lds(
        (const __attribute__((address_space(1))) unsigned int*)g,
        (__attribute__((address_space(3))) unsigned int*)l, 16, 0, 0);
}

// ---- prep: block c handles codes [c*64, c*64+64)  (verified R4-R17) ----
__global__ __launch_bounds__(256)
void vq_prep(const float* __restrict__ E, float* __restrict__ ET,
             char* __restrict__ ETbf, float* __restrict__ norms) {
    __shared__ float tile[256][64];   // [k][code_local]
    const int t = threadIdx.x;
    const int c = blockIdx.x;

    #pragma unroll
    for (int i = 0; i < 16; ++i) {
        const int k = i * 16 + (t >> 4);
        *(float4*)&tile[k][(t & 15) * 4] =
            *(const float4*)&E[(size_t)k * Kcode + c * 64 + (t & 15) * 4];
    }
    __syncthreads();

    if (t < 64) {
        float s = 0.f;
        for (int k = 0; k < 256; ++k) s = fmaf(tile[k][t], tile[k][t], s);
        norms[c * 64 + t] = s;
    }
    #pragma unroll
    for (int j = 0; j < 16; ++j) {
        const int cl = t >> 2, k0 = (t & 3) * 64 + j * 4;
        float4 v = {tile[k0][cl], tile[k0 + 1][cl], tile[k0 + 2][cl], tile[k0 + 3][cl]};
        *(float4*)&ET[(size_t)(c * 64 + cl) * Ddim + k0] = v;
    }
    // ETbf fragment-linear: group G (16 codes) at byte G*8192 + s*1024 + l*16;
    // lane l: code = G*16 + (l&15), k = s*32 + (l>>4)*8 .. +8
    #pragma unroll
    for (int i = 0; i < 8; ++i) {
        const int wd = i * 256 + t;
        const int g = wd >> 9, s = (wd >> 6) & 7, l = wd & 63;
        const int cl = g * 16 + (l & 15);
        const int k0 = s * 32 + (l >> 4) * 8;
        union { uint4 v; ushort_t u[8]; } pk;
        #pragma unroll
        for (int j = 0; j < 8; ++j) pk.u[j] = f2bf(tile[k0 + j][cl]);
        *(uint4*)(ETbf + (size_t)c * 32768 + (size_t)wd * 16) = pk.v;
    }
}

// ---- fused: 128 rows x all 1024 codes per block; 8 phases of 128 codes ----
__global__ __launch_bounds__(512, 1)
void vq_fused(const float* __restrict__ X, const char* __restrict__ ETbf,
              const float* __restrict__ ET, const float* __restrict__ norms,
              float* __restrict__ out, double* __restrict__ partials) {
    __shared__ __align__(16) char smB[2][65536];   // 128 codes x 256 dims bf16
    __shared__ float    nrmS[1024];
    __shared__ u64      candS[128][CAP];
    __shared__ int      cntS[128];
    __shared__ unsigned escS[128];
    __shared__ float    rowminS[128];
    __shared__ double   lred[8];
    // LDS: 131072+4096+6144+512+512+512+64 = 142912 B -> capacity 1/CU

    const int t = threadIdx.x;
    const int l = t & 63;
    const int w = t >> 6;           // wave 0..7
    const int l15 = l & 15, lq = l >> 4;
    const int row0 = blockIdx.x * 128;

    if (t < 128) { cntS[t] = 0; escS[t] = 0; }
    #pragma unroll
    for (int i = 0; i < 2; ++i) nrmS[i * 512 + t] = norms[i * 512 + t];

    // ---- A fragments: wave w owns rows [row0 + w*16, +16)  (32 VGPRs) ----
    bf16x8 afrag[8];
    #pragma unroll
    for (int s = 0; s < 8; ++s) {
        const float* xp = X + (size_t)(row0 + w * 16 + l15) * Ddim
                          + s * 32 + lq * 8;
        const float4 v0 = *(const float4*)xp;
        const float4 v1 = *(const float4*)(xp + 4);
        union { bf16x8 v; ushort_t u[8]; } pk;
        pk.u[0] = f2bf(v0.x); pk.u[1] = f2bf(v0.y);
        pk.u[2] = f2bf(v0.z); pk.u[3] = f2bf(v0.w);
        pk.u[4] = f2bf(v1.x); pk.u[5] = f2bf(v1.y);
        pk.u[6] = f2bf(v1.z); pk.u[7] = f2bf(v1.w);
        afrag[s] = pk.v;
    }

    // per-lane top-3 tracking (values; indices only for top-2)
    float b1v[4], b2v[4], b3v[4];
    int   b1i[4], b2i[4];
    #pragma unroll
    for (int r = 0; r < 4; ++r) {
        b1v[r] = 3.4e38f; b2v[r] = 3.4e38f; b3v[r] = 3.4e38f;
        b1i[r] = 0; b2i[r] = 0;
    }

    auto STAGE = [&](int c, int buf) {
        const char* src = ETbf + ((size_t)c << 16);
        #pragma unroll
        for (int i = 0; i < 8; ++i)
            gload_lds16(src + (size_t)((i * 512 + t) << 4),
                        smB[buf] + ((i * 512 + (t & ~63)) << 4));
    };

    auto COMPUTE = [&](int c, int buf) {
        #pragma unroll
        for (int g = 0; g < 8; ++g) {
            const char* base = smB[buf] + g * 8192 + l * 16;
            bf16x8 b[8];
            #pragma unroll
            for (int s = 0; s < 8; ++s) b[s] = *(const bf16x8*)(base + s * 1024);
            f32x4 a0 = {0.f, 0.f, 0.f, 0.f}, a1 = {0.f, 0.f, 0.f, 0.f};
            #pragma unroll
            for (int s = 0; s < 8; s += 2) {     // two independent chains
                a0 = __builtin_amdgcn_mfma_f32_16x16x32_bf16(afrag[s], b[s], a0, 0, 0, 0);
                a1 = __builtin_amdgcn_mfma_f32_16x16x32_bf16(afrag[s + 1], b[s + 1], a1, 0, 0, 0);
            }
            const int code = c * 128 + g * 16 + l15;
            const float nk = nrmS[code];
            #pragma unroll
            for (int r = 0; r < 4; ++r) {
                const float sc = fmaf(-2.f, a0[r] + a1[r], nk);
                if (sc < b1v[r]) {
                    b3v[r] = b2v[r]; b2v[r] = b1v[r]; b2i[r] = b1i[r];
                    b1v[r] = sc; b1i[r] = code;
                } else if (sc < b2v[r]) {
                    b3v[r] = b2v[r]; b2v[r] = sc; b2i[r] = code;
                } else if (sc < b3v[r]) {
                    b3v[r] = sc;
                }
            }
        }
    };

    // ---- chunk pipeline: 8 chunks of 128 codes, double-buffered ----
    STAGE(0, 0);
    __syncthreads();
    for (int c = 0; c < 8; ++c) {
        if (c < 7) STAGE(c + 1, (c + 1) & 1);
        COMPUTE(c, c & 1);
        __syncthreads();
    }

    // ---- emission with FINAL block threshold ----
    #pragma unroll
    for (int r = 0; r < 4; ++r) {
        float m = b1v[r];
        #pragma unroll
        for (int off = 1; off < 16; off <<= 1)
            m = fminf(m, __shfl_xor(m, off, 16));
        const int rowL = w * 16 + lq * 4 + r;
        if (l15 == 0) rowminS[rowL] = m;
        const float thr = m + MARGIN;
        if (b1v[r] <= thr) {
            const int p = atomicAdd(&cntS[rowL], 1);
            if (p < CAP) candS[rowL][p] = packKey(b1v[r], b1i[r]);
        }
        if (b2v[r] <= thr) {
            const int p = atomicAdd(&cntS[rowL], 1);
            if (p < CAP) candS[rowL][p] = packKey(b2v[r], b2i[r]);
        }
        if (b3v[r] <= thr)
            atomicOr(&escS[rowL], 1u << l15);   // lane may have dropped a 4th+
    }
    __syncthreads();

    // ---- resolve epilogue: wave handles its own 16 rows ----
    double lacc = 0.0;
    for (int rr = 0; rr < 16; ++rr) {
        const int rowL = w * 16 + rr;
        const int row = row0 + rowL;
        const float4 x4 = *(const float4*)&X[(size_t)row * Ddim + l * 4];
        const int n = cntS[rowL];
        const unsigned em = escS[rowL];

        // shuffle-parallel exact fp32 rescore (one code, all 64 lanes)
        auto rescoreS = [&](int code) -> float {
            const float4 e4 = *(const float4*)&ET[(size_t)code * Ddim + l * 4];
            float d = x4.x * e4.x;
            d = fmaf(x4.y, e4.y, d);
            d = fmaf(x4.z, e4.z, d);
            d = fmaf(x4.w, e4.w, d);
            #pragma unroll
            for (int off = 1; off < 64; off <<= 1) d += __shfl_xor(d, off, 64);
            return nrmS[code] - 2.f * d;
        };
        // per-lane serial exact fp32 score (lane-parallel over codes)
        auto laneDot = [&](int cd) -> float {
            const float* ep = ET + (size_t)cd * Ddim;
            const float* xp = X + (size_t)row * Ddim;
            float s0 = 0.f, s1 = 0.f, s2 = 0.f, s3 = 0.f;
            for (int d0 = 0; d0 < 64; ++d0) {
                const float4 e4 = *(const float4*)(ep + d0 * 4);
                const float4 xx = *(const float4*)(xp + d0 * 4);
                s0 = fmaf(xx.x, e4.x, s0); s1 = fmaf(xx.y, e4.y, s1);
                s2 = fmaf(xx.z, e4.z, s2); s3 = fmaf(xx.w, e4.w, s3);
            }
            return nrmS[cd] - 2.f * ((s0 + s1) + (s2 + s3));
        };

        int code;
        if (n == 1 && em == 0) {
            code = (int)(candS[rowL][0] & 0xffffffffu);   // provably the argmin
        } else if (n >= 1 && n <= CAP) {
            float bS = 3.4e38f; int bC = 0x7fffffff;
            for (int j = 0; j < n; ++j) {
                const int cd = (int)(candS[rowL][j] & 0xffffffffu);
                const float s = rescoreS(cd);
                if (s < bS || (s == bS && cd < bC)) { bS = s; bC = cd; }
            }
            unsigned m2 = em;
            while (m2) {   // escalated lane: rescan its 64 codes, lane-parallel
                const int c15 = __ffs(m2) - 1; m2 &= m2 - 1;
                const int cd = l * 16 + c15;
                u64 k = packKey(laneDot(cd), cd);
                #pragma unroll
                for (int off = 1; off < 64; off <<= 1) {
                    const u64 o = __shfl_xor(k, off, 64);
                    if (o < k) k = o;
                }
                const float s = unpackScore(k);
                const int cd2 = (int)(k & 0xffffffffu);
                if (s < bS || (s == bS && cd2 < bC)) { bS = s; bC = cd2; }
            }
            code = bC;
        } else {   // overflow (rare): bounded lane-parallel full scan
            u64 k = ~0ULL;
            for (int i = 0; i < 16; ++i) {
                const int cd = i * 64 + l;
                const u64 k2 = packKey(laneDot(cd), cd);
                if (k2 < k) k = k2;
            }
            #pragma unroll
            for (int off = 1; off < 64; off <<= 1) {
                const u64 o = __shfl_xor(k, off, 64);
                if (o < k) k = o;
            }
            code = (int)(k & 0xffffffffu);
        }

        const float4 q4 = *(const float4*)&ET[(size_t)code * Ddim + l * 4];
        *(float4*)&out[(size_t)row * Ddim + l * 4] = q4;
        const double dx = (double)(q4.x - x4.x), dy = (double)(q4.y - x4.y);
        const double dz = (double)(q4.z - x4.z), dw = (double)(q4.w - x4.w);
        lacc += dx * dx + dy * dy + dz * dz + dw * dw;
    }
    #pragma unroll
    for (int off = 32; off; off >>= 1) lacc += __shfl_down(lacc, off, 64);
    if (l == 0) lred[w] = lacc;
    __syncthreads();
    if (t == 0) {
        double s = 0.0;
        #pragma unroll
        for (int i = 0; i < 8; ++i) s += lred[i];
        partials[blockIdx.x] = s;
    }
}

// ---- final loss ----
__global__ __launch_bounds__(256)
void vq_lossk(const double* __restrict__ partials, float* __restrict__ lossOut) {
    __shared__ double red[4];
    double v = 0.0;
    for (int i = threadIdx.x; i < 256; i += 256) v += partials[i];
    #pragma unroll
    for (int off = 32; off; off >>= 1) v += __shfl_down(v, off, 64);
    const int lane = threadIdx.x & 63, grp = threadIdx.x >> 6;
    if (lane == 0) red[grp] = v;
    __syncthreads();
    if (threadIdx.x == 0)
        lossOut[0] = (float)(1.25 * (red[0] + red[1] + red[2] + red[3]) /
                             (double)((size_t)Mrows * Ddim));
}

// ===========================================================================
extern "C" void kernel_launch(void* const* d_in, const int* in_sizes, int n_in,
                              void* d_out, int out_size, void* d_ws, size_t ws_size,
                              hipStream_t stream) {
    const float* X = (const float*)d_in[0];
    const float* E = (const float*)d_in[1];
    float* out = (float*)d_out;
    char* ws = (char*)d_ws;

    // workspace: partials 2KB | ET 1MB | ETbf 512KB | norms 4KB  (~1.5MB)
    const size_t partB = 256 * 8;
    const size_t etB   = (size_t)Kcode * Ddim * 4;
    const size_t etbfB = (size_t)Kcode * Ddim * 2;
    char* p = ws;
    double* partials = (double*)p;  p += partB;
    float*  ET       = (float*)p;   p += etB;
    char*   ETbf     = p;           p += etbfB;
    float*  norms    = (float*)p;

    vq_prep<<<16, 256, 0, stream>>>(E, ET, ETbf, norms);
    vq_fused<<<Mrows / 128, 512, 0, stream>>>(X, ETbf, ET, norms, out, partials);
    vq_lossk<<<1, 256, 0, stream>>>(partials, out + (size_t)Mrows * Ddim);
}

// Round 19
// 80.522 us; speedup vs baseline: 2.1406x; 2.1406x over previous
//
#include <hip/hip_runtime.h>

// ---------------------------------------------------------------------------
// VectorQuantizer FINAL == R17 verbatim (best measured: 80.58us total).
// Session ledger: fp32 tiled 340 -> code-split 280 -> MFMA+rescore 152 ->
// fused straggler-free 89 -> 16-phase 80.6. The exactly-2-resident-blocks
// property is load-bearing (phases of the two blocks interleave to hide
// barrier drain): 1/CU (R18) and >2/CU (R10-R15) all regressed. Occupancy,
// pipeline-depth, vmcnt, geometry, and MFMA-shape levers each measured
// null/negative; phase-count halving was the only repeatable win and is
// capacity-limited at 16 phases.
// Exactness: bf16-MFMA scores + margin-superset candidates (MARGIN=0.25 >>
// 2*bf16 dot error ~0.14) + exact fp32 rescore w/ first-min tie-break;
// all rare paths lane-parallel bounded.
// ---------------------------------------------------------------------------

constexpr int Mrows = 32768;
constexpr int Ddim  = 256;
constexpr int Kcode = 1024;

constexpr int   CAP    = 16;     // overflow (n>16) -> bounded full scan
constexpr float MARGIN = 0.25f;

typedef unsigned long long u64;
typedef unsigned short ushort_t;
typedef __attribute__((ext_vector_type(8))) short bf16x8;
typedef __attribute__((ext_vector_type(4))) float f32x4;

__device__ inline u64 packKey(float v, int idx) {
    unsigned u = __float_as_uint(v);
    u = (u & 0x80000000u) ? ~u : (u | 0x80000000u);   // order-preserving
    return ((u64)u << 32) | (unsigned)idx;
}
__device__ inline float unpackScore(u64 k) {
    unsigned v = (unsigned)(k >> 32);
    unsigned orig = (v & 0x80000000u) ? (v ^ 0x80000000u) : ~v;
    return __uint_as_float(orig);
}
__device__ inline ushort_t f2bf(float f) {   // RTN-even
    unsigned u = __float_as_uint(f);
    return (ushort_t)((u + 0x7fffu + ((u >> 16) & 1u)) >> 16);
}
__device__ inline void gload_lds16(const void* g, void* l) {
    __builtin_amdgcn_global_load_lds(
        (const __attribute__((address_space(1))) unsigned int*)g,
        (__attribute__((address_space(3))) unsigned int*)l, 16, 0, 0);
}

// ---- prep: block c handles codes [c*64, c*64+64) ----
__global__ __launch_bounds__(256)
void vq_prep(const float* __restrict__ E, float* __restrict__ ET,
             char* __restrict__ ETbf, float* __restrict__ norms) {
    __shared__ float tile[256][64];   // [k][code_local]
    const int t = threadIdx.x;
    const int c = blockIdx.x;

    #pragma unroll
    for (int i = 0; i < 16; ++i) {
        const int k = i * 16 + (t >> 4);
        *(float4*)&tile[k][(t & 15) * 4] =
            *(const float4*)&E[(size_t)k * Kcode + c * 64 + (t & 15) * 4];
    }
    __syncthreads();

    if (t < 64) {
        float s = 0.f;
        for (int k = 0; k < 256; ++k) s = fmaf(tile[k][t], tile[k][t], s);
        norms[c * 64 + t] = s;
    }
    #pragma unroll
    for (int j = 0; j < 16; ++j) {
        const int cl = t >> 2, k0 = (t & 3) * 64 + j * 4;
        float4 v = {tile[k0][cl], tile[k0 + 1][cl], tile[k0 + 2][cl], tile[k0 + 3][cl]};
        *(float4*)&ET[(size_t)(c * 64 + cl) * Ddim + k0] = v;
    }
    // ETbf fragment-linear: group G (16 codes) at byte G*8192 + s*1024 + l*16;
    // lane l: code = G*16 + (l&15), k = s*32 + (l>>4)*8 .. +8
    #pragma unroll
    for (int i = 0; i < 8; ++i) {
        const int wd = i * 256 + t;
        const int g = wd >> 9, s = (wd >> 6) & 7, l = wd & 63;
        const int cl = g * 16 + (l & 15);
        const int k0 = s * 32 + (l >> 4) * 8;
        union { uint4 v; ushort_t u[8]; } pk;
        #pragma unroll
        for (int j = 0; j < 8; ++j) pk.u[j] = f2bf(tile[k0 + j][cl]);
        *(uint4*)(ETbf + (size_t)c * 32768 + (size_t)wd * 16) = pk.v;
    }
}

// ---- fused: 64 rows x all 1024 codes per block; 16 phases of 64 codes ----
__global__ __launch_bounds__(256, 2)
void vq_fused(const float* __restrict__ X, const char* __restrict__ ETbf,
              const float* __restrict__ ET, const float* __restrict__ norms,
              float* __restrict__ out, double* __restrict__ partials) {
    __shared__ __align__(16) char smB[2][32768];   // 64 codes x 256 dims bf16
    __shared__ float    nrmS[1024];
    __shared__ u64      candS[64][CAP];
    __shared__ int      cntS[64];
    __shared__ unsigned escS[64];
    __shared__ float    rowminS[64];
    __shared__ double   lred[4];
    // LDS 78624B -> capacity EXACTLY 2 blocks/CU (load-bearing property)

    const int t = threadIdx.x;
    const int l = t & 63;
    const int w = t >> 6;
    const int l15 = l & 15, lq = l >> 4;
    const int row0 = blockIdx.x * 64;

    if (t < 64) { cntS[t] = 0; escS[t] = 0; }
    #pragma unroll
    for (int i = 0; i < 4; ++i) nrmS[i * 256 + t] = norms[i * 256 + t];

    // ---- A fragments: wave w owns rows [row0 + w*16, +16)  (32 VGPRs) ----
    bf16x8 afrag[8];
    #pragma unroll
    for (int s = 0; s < 8; ++s) {
        const float* xp = X + (size_t)(row0 + w * 16 + l15) * Ddim
                          + s * 32 + lq * 8;
        const float4 v0 = *(const float4*)xp;
        const float4 v1 = *(const float4*)(xp + 4);
        union { bf16x8 v; ushort_t u[8]; } pk;
        pk.u[0] = f2bf(v0.x); pk.u[1] = f2bf(v0.y);
        pk.u[2] = f2bf(v0.z); pk.u[3] = f2bf(v0.w);
        pk.u[4] = f2bf(v1.x); pk.u[5] = f2bf(v1.y);
        pk.u[6] = f2bf(v1.z); pk.u[7] = f2bf(v1.w);
        afrag[s] = pk.v;
    }

    // per-lane top-3 tracking (values; indices only for top-2)
    float b1v[4], b2v[4], b3v[4];
    int   b1i[4], b2i[4];
    #pragma unroll
    for (int r = 0; r < 4; ++r) {
        b1v[r] = 3.4e38f; b2v[r] = 3.4e38f; b3v[r] = 3.4e38f;
        b1i[r] = 0; b2i[r] = 0;
    }

    auto STAGE = [&](int c, int buf) {
        const char* src = ETbf + ((size_t)c << 15);
        #pragma unroll
        for (int i = 0; i < 8; ++i)
            gload_lds16(src + (size_t)((i * 256 + t) << 4),
                        smB[buf] + ((i * 256 + (t & ~63)) << 4));
    };

    auto COMPUTE = [&](int c, int buf) {
        #pragma unroll
        for (int g = 0; g < 4; ++g) {
            const char* base = smB[buf] + g * 8192 + l * 16;
            bf16x8 b[8];
            #pragma unroll
            for (int s = 0; s < 8; ++s) b[s] = *(const bf16x8*)(base + s * 1024);
            f32x4 a0 = {0.f, 0.f, 0.f, 0.f}, a1 = {0.f, 0.f, 0.f, 0.f};
            #pragma unroll
            for (int s = 0; s < 8; s += 2) {     // two independent chains
                a0 = __builtin_amdgcn_mfma_f32_16x16x32_bf16(afrag[s], b[s], a0, 0, 0, 0);
                a1 = __builtin_amdgcn_mfma_f32_16x16x32_bf16(afrag[s + 1], b[s + 1], a1, 0, 0, 0);
            }
            const int code = c * 64 + g * 16 + l15;
            const float nk = nrmS[code];
            #pragma unroll
            for (int r = 0; r < 4; ++r) {
                const float sc = fmaf(-2.f, a0[r] + a1[r], nk);
                if (sc < b1v[r]) {
                    b3v[r] = b2v[r]; b2v[r] = b1v[r]; b2i[r] = b1i[r];
                    b1v[r] = sc; b1i[r] = code;
                } else if (sc < b2v[r]) {
                    b3v[r] = b2v[r]; b2v[r] = sc; b2i[r] = code;
                } else if (sc < b3v[r]) {
                    b3v[r] = sc;
                }
            }
        }
    };

    // ---- chunk pipeline: 16 chunks of 64 codes, double-buffered ----
    STAGE(0, 0);
    __syncthreads();
    for (int c = 0; c < 16; ++c) {
        if (c < 15) STAGE(c + 1, (c + 1) & 1);
        COMPUTE(c, c & 1);
        __syncthreads();
    }

    // ---- emission with FINAL block threshold ----
    #pragma unroll
    for (int r = 0; r < 4; ++r) {
        float m = b1v[r];
        #pragma unroll
        for (int off = 1; off < 16; off <<= 1)
            m = fminf(m, __shfl_xor(m, off, 16));
        const int rowL = w * 16 + lq * 4 + r;
        if (l15 == 0) rowminS[rowL] = m;
        const float thr = m + MARGIN;
        if (b1v[r] <= thr) {
            const int p = atomicAdd(&cntS[rowL], 1);
            if (p < CAP) candS[rowL][p] = packKey(b1v[r], b1i[r]);
        }
        if (b2v[r] <= thr) {
            const int p = atomicAdd(&cntS[rowL], 1);
            if (p < CAP) candS[rowL][p] = packKey(b2v[r], b2i[r]);
        }
        if (b3v[r] <= thr)
            atomicOr(&escS[rowL], 1u << l15);   // lane may have dropped a 4th+
    }
    __syncthreads();

    // ---- resolve epilogue: wave handles its own 16 rows ----
    double lacc = 0.0;
    for (int rr = 0; rr < 16; ++rr) {
        const int rowL = w * 16 + rr;
        const int row = row0 + rowL;
        const float4 x4 = *(const float4*)&X[(size_t)row * Ddim + l * 4];
        const int n = cntS[rowL];
        const unsigned em = escS[rowL];

        // shuffle-parallel exact fp32 rescore (one code, all 64 lanes)
        auto rescoreS = [&](int code) -> float {
            const float4 e4 = *(const float4*)&ET[(size_t)code * Ddim + l * 4];
            float d = x4.x * e4.x;
            d = fmaf(x4.y, e4.y, d);
            d = fmaf(x4.z, e4.z, d);
            d = fmaf(x4.w, e4.w, d);
            #pragma unroll
            for (int off = 1; off < 64; off <<= 1) d += __shfl_xor(d, off, 64);
            return nrmS[code] - 2.f * d;
        };
        // per-lane serial exact fp32 score (lane-parallel over codes)
        auto laneDot = [&](int cd) -> float {
            const float* ep = ET + (size_t)cd * Ddim;
            const float* xp = X + (size_t)row * Ddim;
            float s0 = 0.f, s1 = 0.f, s2 = 0.f, s3 = 0.f;
            for (int d0 = 0; d0 < 64; ++d0) {
                const float4 e4 = *(const float4*)(ep + d0 * 4);
                const float4 xx = *(const float4*)(xp + d0 * 4);
                s0 = fmaf(xx.x, e4.x, s0); s1 = fmaf(xx.y, e4.y, s1);
                s2 = fmaf(xx.z, e4.z, s2); s3 = fmaf(xx.w, e4.w, s3);
            }
            return nrmS[cd] - 2.f * ((s0 + s1) + (s2 + s3));
        };

        int code;
        if (n == 1 && em == 0) {
            code = (int)(candS[rowL][0] & 0xffffffffu);   // provably the argmin
        } else if (n >= 1 && n <= CAP) {
            float bS = 3.4e38f; int bC = 0x7fffffff;
            for (int j = 0; j < n; ++j) {
                const int cd = (int)(candS[rowL][j] & 0xffffffffu);
                const float s = rescoreS(cd);
                if (s < bS || (s == bS && cd < bC)) { bS = s; bC = cd; }
            }
            unsigned m2 = em;
            while (m2) {   // escalated lane: rescan its 64 codes, lane-parallel
                const int c15 = __ffs(m2) - 1; m2 &= m2 - 1;
                const int cd = l * 16 + c15;
                u64 k = packKey(laneDot(cd), cd);
                #pragma unroll
                for (int off = 1; off < 64; off <<= 1) {
                    const u64 o = __shfl_xor(k, off, 64);
                    if (o < k) k = o;
                }
                const float s = unpackScore(k);
                const int cd2 = (int)(k & 0xffffffffu);
                if (s < bS || (s == bS && cd2 < bC)) { bS = s; bC = cd2; }
            }
            code = bC;
        } else {   // overflow (P ~ 0): bounded lane-parallel full scan
            u64 k = ~0ULL;
            for (int i = 0; i < 16; ++i) {
                const int cd = i * 64 + l;
                const u64 k2 = packKey(laneDot(cd), cd);
                if (k2 < k) k = k2;
            }
            #pragma unroll
            for (int off = 1; off < 64; off <<= 1) {
                const u64 o = __shfl_xor(k, off, 64);
                if (o < k) k = o;
            }
            code = (int)(k & 0xffffffffu);
        }

        const float4 q4 = *(const float4*)&ET[(size_t)code * Ddim + l * 4];
        *(float4*)&out[(size_t)row * Ddim + l * 4] = q4;
        const double dx = (double)(q4.x - x4.x), dy = (double)(q4.y - x4.y);
        const double dz = (double)(q4.z - x4.z), dw = (double)(q4.w - x4.w);
        lacc += dx * dx + dy * dy + dz * dz + dw * dw;
    }
    #pragma unroll
    for (int off = 32; off; off >>= 1) lacc += __shfl_down(lacc, off, 64);
    if (l == 0) lred[w] = lacc;
    __syncthreads();
    if (t == 0)
        partials[blockIdx.x] = lred[0] + lred[1] + lred[2] + lred[3];
}

// ---- final loss ----
__global__ __launch_bounds__(256)
void vq_lossk(const double* __restrict__ partials, float* __restrict__ lossOut) {
    __shared__ double red[4];
    double v = 0.0;
    for (int i = threadIdx.x; i < 512; i += 256) v += partials[i];
    #pragma unroll
    for (int off = 32; off; off >>= 1) v += __shfl_down(v, off, 64);
    const int lane = threadIdx.x & 63, grp = threadIdx.x >> 6;
    if (lane == 0) red[grp] = v;
    __syncthreads();
    if (threadIdx.x == 0)
        lossOut[0] = (float)(1.25 * (red[0] + red[1] + red[2] + red[3]) /
                             (double)((size_t)Mrows * Ddim));
}

// ===========================================================================
extern "C" void kernel_launch(void* const* d_in, const int* in_sizes, int n_in,
                              void* d_out, int out_size, void* d_ws, size_t ws_size,
                              hipStream_t stream) {
    const float* X = (const float*)d_in[0];
    const float* E = (const float*)d_in[1];
    float* out = (float*)d_out;
    char* ws = (char*)d_ws;

    // workspace: partials 4KB | ET 1MB | ETbf 512KB | norms 4KB  (~1.5MB)
    const size_t partB = 512 * 8;
    const size_t etB   = (size_t)Kcode * Ddim * 4;
    const size_t etbfB = (size_t)Kcode * Ddim * 2;
    char* p = ws;
    double* partials = (double*)p;  p += partB;
    float*  ET       = (float*)p;   p += etB;
    char*   ETbf     = p;           p += etbfB;
    float*  norms    = (float*)p;

    vq_prep<<<16, 256, 0, stream>>>(E, ET, ETbf, norms);
    vq_fused<<<Mrows / 64, 256, 0, stream>>>(X, ETbf, ET, norms, out, partials);
    vq_lossk<<<1, 256, 0, stream>>>(partials, out + (size_t)Mrows * Ddim);
}